// Round 8
// baseline (177.980 us; speedup 1.0000x reference)
//
#include <hip/hip_runtime.h>
#include <hip/hip_bf16.h>
#include <cstdint>

// TripCenterLoss_min_margin: B=8192, C=4096, D=2048
// loss = mean_b max(margin + w*dist_own(b) - (1-w)*min_{c!=lbl} dist(b,c), 0)
constexpr int NB = 8192;
constexpr int NC = 4096;
constexpr int ND = 2048;

// ---- prefetch-pipelined 256x256 GEMM, 32x32x16 MFMA ----
constexpr int BM = 256, BN = 256, BK = 64;
constexpr int NRB = NB / BM;    // 32
constexpr int NCB = NC / BN;    // 16
constexpr int NWG = NRB * NCB;  // 512  (%8==0 -> bijective XCD swizzle)
constexpr int NT = ND / BK;     // 32 K-tiles
constexpr int NIT = NT / 2;     // 16 iterations (2 K-tiles each)
constexpr int NSLOT = NC / 64;  // 64 pmin slots per row

typedef __attribute__((ext_vector_type(8))) __bf16 bf16x8;
typedef __attribute__((ext_vector_type(8))) unsigned short usvec8;
typedef __attribute__((ext_vector_type(4))) unsigned short usvec4;
typedef __attribute__((ext_vector_type(16))) float f32x16;

__device__ inline unsigned short f2bf(float f) {
  unsigned int u = __float_as_uint(f);
  u += 0x7fffu + ((u >> 16) & 1u);  // RNE
  return (unsigned short)(u >> 16);
}

// ---------------- fused norms + f32->bf16 convert ----------------
__global__ __launch_bounds__(256) void prep_kernel(const float* __restrict__ x,
                                                   const float* __restrict__ cen,
                                                   float* __restrict__ xnorm,
                                                   float* __restrict__ cnorm,
                                                   unsigned short* __restrict__ xb,
                                                   unsigned short* __restrict__ cb) {
  int row = blockIdx.x;
  const float* src;
  float* ndst;
  unsigned short* bdst;
  if (row < NB) { src = x + (size_t)row * ND; ndst = xnorm + row; bdst = xb + (size_t)row * ND; }
  else { row -= NB; src = cen + (size_t)row * ND; ndst = cnorm + row; bdst = cb + (size_t)row * ND; }
  float s = 0.f;
  #pragma unroll
  for (int it = 0; it < 2; it++) {
    int i = threadIdx.x * 4 + it * 1024;
    float4 v = *(const float4*)(src + i);
    s += v.x * v.x + v.y * v.y + v.z * v.z + v.w * v.w;
    usvec4 u;
    u[0] = f2bf(v.x); u[1] = f2bf(v.y); u[2] = f2bf(v.z); u[3] = f2bf(v.w);
    *(usvec4*)(bdst + i) = u;
  }
  #pragma unroll
  for (int m = 1; m < 64; m <<= 1) s += __shfl_xor(s, m);
  __shared__ float red[4];
  int lane = threadIdx.x & 63, wid = threadIdx.x >> 6;
  if (lane == 0) red[wid] = s;
  __syncthreads();
  if (threadIdx.x == 0) *ndst = red[0] + red[1] + red[2] + red[3];
}

// ---------------- norms only (fallback path) ----------------
__global__ __launch_bounds__(256) void norms_kernel(const float* __restrict__ x,
                                                    const float* __restrict__ cen,
                                                    float* __restrict__ xnorm,
                                                    float* __restrict__ cnorm) {
  int row = blockIdx.x;
  const float* src;
  float* dst;
  if (row < NB) { src = x + (size_t)row * ND; dst = xnorm + row; }
  else          { src = cen + (size_t)(row - NB) * ND; dst = cnorm + (row - NB); }
  float s = 0.f;
  #pragma unroll
  for (int it = 0; it < 2; it++) {
    int i = threadIdx.x * 4 + it * 1024;
    float4 v = *(const float4*)(src + i);
    s += v.x * v.x + v.y * v.y + v.z * v.z + v.w * v.w;
  }
  #pragma unroll
  for (int m = 1; m < 64; m <<= 1) s += __shfl_xor(s, m);
  __shared__ float red[4];
  int lane = threadIdx.x & 63, wid = threadIdx.x >> 6;
  if (lane == 0) red[wid] = s;
  __syncthreads();
  if (threadIdx.x == 0) *dst = red[0] + red[1] + red[2] + red[3];
}

// ---------------- async global->LDS ----------------
__device__ inline void gload_lds16(const void* g, void* lds) {
  __builtin_amdgcn_global_load_lds(
      (const __attribute__((address_space(1))) unsigned int*)g,
      (__attribute__((address_space(3))) unsigned int*)lds, 16, 0, 0);
}

// Stage one half-tile (256 rows x 32 k, 16KB) into a contiguous LDS region.
// LINEAR LDS dest; XOR swizzle applied by permuting the GLOBAL source
// (involution, rule 21): physical chunk pc = kc ^ ((row>>1)&3).
// R4-verified: 0 bank conflicts on the swizzled ds_read_b128 pattern.
__device__ __forceinline__ void stage_half(unsigned short* reg, const unsigned short* gsrc,
                                           int row0, int kcol0, int wid, int lane) {
  #pragma unroll
  for (int i = 0; i < 2; i++) {
    int c = (wid * 2 + i) * 64 + lane;        // chunk index 0..1023
    int row = c >> 2;                         // 4 chunks (64B) per row
    int kc = (c & 3) ^ ((row >> 1) & 3);      // logical k-chunk at this physical slot
    gload_lds16(gsrc + (size_t)(row0 + row) * ND + kcol0 + kc * 8,
                (char*)reg + (size_t)c * 16);
  }
}

// ---------------- prefetch-pipelined 256^2 fused GEMM (32x32x16) ----------------
// 8 phases per iter (2 K-tiles); phase = one K-step of 16.
// Phase p: barrier | issue 6 ds_read_b128 for frags(p+1) + 1 stage_half |
//          sched_barrier | MFMA frags(p) x8 (compiler auto lgkmcnt(6)) |
//          [vmcnt(6) at odd phases].
// Reads execute on the LDS pipe DURING the MFMA cluster (counted lgkm).
//
// Region ledger (stage -> first prefetch-read, all >=5 phases apart):
//   p0:(1,B,kh1)@t+1 -> read p5       p1:(0,A,kh0)@t+2 -> read p7
//   p2:(0,B,kh0)@t+2 -> read p7       p3:(0,A,kh1)@t+2 -> read next p1
//   p4:(0,B,kh1)@t+2 -> read next p1  p5:(1,A,kh0)@t+3 -> read next p3
//   p6:(1,B,kh0)@t+3 -> read next p3  p7:(1,A,kh1)@t+3 -> read next p5
// vmcnt(6) at p1/p3/p5/p7: after each, outstanding = newest 3 stages, so a
// stage issued at q is drained by the vmcnt at q+3 (or earlier) and ordered
// against readers by the next phase-top barrier -> every first-read above is
// covered (worst case: p1/p2 stages drained at p5, read p7; p0 drained at p3,
// read p5; p7 drained at next p3, read next p5).
// Stage-target stability: region staged at p was last prefetch-READ at p-2;
// those reads retire at p-1's auto-lgkmcnt (in-order DS) before p-1's MFMA,
// and p's top barrier orders all waves' retirement before the DMA issue.
__global__ __launch_bounds__(512, 2) void gemm8_kernel(
    const unsigned short* __restrict__ xb, const unsigned short* __restrict__ cb,
    const float* __restrict__ xnorm, const float* __restrict__ cnorm,
    const int* __restrict__ labels,
    float* __restrict__ own, float* __restrict__ pmin) {
  // [buf][mat A=0/B=1][khalf][256 rows x 32 k]; 128 KiB total.
  __shared__ unsigned short lds[2][2][2][256 * 32];

  const int tid = threadIdx.x;
  const int lane = tid & 63;
  const int wid = tid >> 6;
  const int llo32 = lane & 31;
  const int hi = lane >> 5;
  // un-swizzle on read (32x32 frag: row = lane&31, kc = 2*ks + hi):
  // phys chunk = (2ks ^ hi) ^ ((row>>1)&3) -> byte = ((hi^rx)<<4) ^ (ks<<5)
  const int rx = (llo32 >> 1) & 3;
  const int swk0 = (hi ^ rx) << 4;
  const int swk1 = swk0 ^ 32;

  int bid = blockIdx.x;
  int swz = (bid & 7) * (NWG / 8) + (bid >> 3);
  const int brow0 = (swz / NCB) * BM;
  const int bcol0 = (swz % NCB) * BN;
  const int wr = wid >> 2, wc = wid & 3;  // 2x4 wave grid: wave output 128x64

  f32x16 acc[4][2];
  #pragma unroll
  for (int m = 0; m < 4; m++)
    #pragma unroll
    for (int n = 0; n < 2; n++)
      acc[m][n] = (f32x16)(0.f);

  bf16x8 fa0[4], fb0[2], fa1[4], fb1[2];

// read frags for (BUF, KH, KS) into (FA, FB): 4 A + 2 B ds_read_b128
#define RD(FA, FB, BUF, KH, KS)                                                \
  {                                                                            \
    const char* Ar = (const char*)&lds[BUF][0][KH][0];                         \
    const char* Br = (const char*)&lds[BUF][1][KH][0];                         \
    const int swk = (KS) ? swk1 : swk0;                                        \
    _Pragma("unroll") for (int m = 0; m < 4; m++)                              \
        FA[m] = *(const bf16x8*)(Ar + (wr * 128 + m * 32 + llo32) * 64 + swk); \
    _Pragma("unroll") for (int n = 0; n < 2; n++)                              \
        FB[n] = *(const bf16x8*)(Br + (wc * 64 + n * 32 + llo32) * 64 + swk);  \
  }

// phase: barrier | prefetch-read frags(p+1) + stage | MFMA frags(p) | vmcnt
#define PH(FAc, FBc, FAn, FBn, NBUF, NKH, NKS, STAGE_STMT, VM_STMT)            \
  {                                                                            \
    __builtin_amdgcn_s_barrier();                                              \
    __builtin_amdgcn_sched_barrier(0);                                         \
    RD(FAn, FBn, NBUF, NKH, NKS);                                              \
    STAGE_STMT;                                                                \
    __builtin_amdgcn_sched_barrier(0);                                         \
    __builtin_amdgcn_s_setprio(1);                                             \
    _Pragma("unroll") for (int m = 0; m < 4; m++)                              \
      _Pragma("unroll") for (int n = 0; n < 2; n++)                            \
        acc[m][n] = __builtin_amdgcn_mfma_f32_32x32x16_bf16(FAc[m], FBc[n],    \
                                                            acc[m][n], 0, 0, 0); \
    __builtin_amdgcn_s_setprio(0);                                             \
    __builtin_amdgcn_sched_barrier(0);                                         \
    VM_STMT;                                                                   \
  }

  // prologue: t0 {A.kh0,B.kh0,A.kh1,B.kh1}, t1 {A.kh0,B.kh0,A.kh1} = 14 loads;
  // vmcnt(6) -> all of t0 landed, outstanding = t1's 3 stages (6 loads),
  // matching the steady-state p0-top invariant {p5,p6,p7}.
  stage_half(&lds[0][0][0][0], xb, brow0, 0, wid, lane);
  stage_half(&lds[0][1][0][0], cb, bcol0, 0, wid, lane);
  stage_half(&lds[0][0][1][0], xb, brow0, 32, wid, lane);
  stage_half(&lds[0][1][1][0], cb, bcol0, 32, wid, lane);
  stage_half(&lds[1][0][0][0], xb, brow0, 64, wid, lane);
  stage_half(&lds[1][1][0][0], cb, bcol0, 64, wid, lane);
  stage_half(&lds[1][0][1][0], xb, brow0, 96, wid, lane);
  asm volatile("s_waitcnt vmcnt(6)" ::: "memory");
  __builtin_amdgcn_s_barrier();
  __builtin_amdgcn_sched_barrier(0);
  RD(fa0, fb0, 0, 0, 0);  // frags(p0): tile 0, kh0, kstep 0

  for (int it = 0; it < NIT - 1; ++it) {
    const int t = 2 * it;
    const int k1 = (t + 1) * BK, k2 = (t + 2) * BK, k3 = (t + 3) * BK;
    PH(fa0, fb0, fa1, fb1, 0, 0, 1,
       stage_half(&lds[1][1][1][0], cb, bcol0, k1 + 32, wid, lane), (void)0)
    PH(fa1, fb1, fa0, fb0, 0, 1, 0,
       stage_half(&lds[0][0][0][0], xb, brow0, k2, wid, lane),
       asm volatile("s_waitcnt vmcnt(6)" ::: "memory"))
    PH(fa0, fb0, fa1, fb1, 0, 1, 1,
       stage_half(&lds[0][1][0][0], cb, bcol0, k2, wid, lane), (void)0)
    PH(fa1, fb1, fa0, fb0, 1, 0, 0,
       stage_half(&lds[0][0][1][0], xb, brow0, k2 + 32, wid, lane),
       asm volatile("s_waitcnt vmcnt(6)" ::: "memory"))
    PH(fa0, fb0, fa1, fb1, 1, 0, 1,
       stage_half(&lds[0][1][1][0], cb, bcol0, k2 + 32, wid, lane), (void)0)
    PH(fa1, fb1, fa0, fb0, 1, 1, 0,
       stage_half(&lds[1][0][0][0], xb, brow0, k3, wid, lane),
       asm volatile("s_waitcnt vmcnt(6)" ::: "memory"))
    PH(fa0, fb0, fa1, fb1, 1, 1, 1,
       stage_half(&lds[1][1][0][0], cb, bcol0, k3, wid, lane), (void)0)
    PH(fa1, fb1, fa0, fb0, 0, 0, 0,
       stage_half(&lds[1][0][1][0], xb, brow0, k3 + 32, wid, lane),
       asm volatile("s_waitcnt vmcnt(6)" ::: "memory"))
  }
  // tail iter (t=30,31): only (1,B,kh1)@t31 left to stage; vmcnt(0) at p3
  // guarantees it lands before its p5-top read (p4 barrier orders).
  {
    const int k1 = (NT - 1) * BK;
    PH(fa0, fb0, fa1, fb1, 0, 0, 1,
       stage_half(&lds[1][1][1][0], cb, bcol0, k1 + 32, wid, lane), (void)0)
    PH(fa1, fb1, fa0, fb0, 0, 1, 0, (void)0,
       asm volatile("s_waitcnt vmcnt(6)" ::: "memory"))
    PH(fa0, fb0, fa1, fb1, 0, 1, 1, (void)0, (void)0)
    PH(fa1, fb1, fa0, fb0, 1, 0, 0, (void)0,
       asm volatile("s_waitcnt vmcnt(0)" ::: "memory"))
    PH(fa0, fb0, fa1, fb1, 1, 0, 1, (void)0, (void)0)
    PH(fa1, fb1, fa0, fb0, 1, 1, 0, (void)0, (void)0)
    PH(fa0, fb0, fa1, fb1, 1, 1, 1, (void)0, (void)0)
    // final phase: no reads, no stage; compiler auto-inserts lgkmcnt(0)
    __builtin_amdgcn_s_setprio(1);
    #pragma unroll
    for (int m = 0; m < 4; m++)
      #pragma unroll
      for (int n = 0; n < 2; n++)
        acc[m][n] = __builtin_amdgcn_mfma_f32_32x32x16_bf16(fa1[m], fb1[n],
                                                            acc[m][n], 0, 0, 0);
    __builtin_amdgcn_s_setprio(0);
  }

  // ---- epilogue: dist = xn + cn - 2*dot; own-col; per-row min ----
  // 32x32 C/D layout (m74/m101-verified): col = lane&31,
  // row = (reg&3) + 8*(reg>>2) + 4*(lane>>5), reg in [0,16)
  const int col0 = bcol0 + wc * 64 + llo32;
  const int col1 = col0 + 32;
  const float cn0 = cnorm[col0];
  const float cn1 = cnorm[col1];
  const int cslot = bcol0 / 64 + wc;
  #pragma unroll
  for (int m = 0; m < 4; m++) {
    #pragma unroll
    for (int g = 0; g < 4; g++) {
      const int r0 = brow0 + wr * 128 + m * 32 + hi * 4 + g * 8;
      float4 xn4 = *(const float4*)(xnorm + r0);
      int4 lb4 = *(const int4*)(labels + r0);
      #pragma unroll
      for (int j = 0; j < 4; j++) {
        const int reg = g * 4 + j;
        const int row = r0 + j;
        const float xnv = (j == 0) ? xn4.x : (j == 1) ? xn4.y : (j == 2) ? xn4.z : xn4.w;
        const int lbl = (j == 0) ? lb4.x : (j == 1) ? lb4.y : (j == 2) ? lb4.z : lb4.w;
        float d0 = xnv + cn0 - 2.0f * acc[m][0][reg];
        float d1 = xnv + cn1 - 2.0f * acc[m][1][reg];
        float rmin = 1e38f;
        if (col0 == lbl) own[row] = d0; else rmin = d0;
        if (col1 == lbl) own[row] = d1; else rmin = fminf(rmin, d1);
        rmin = fminf(rmin, __shfl_xor(rmin, 1));
        rmin = fminf(rmin, __shfl_xor(rmin, 2));
        rmin = fminf(rmin, __shfl_xor(rmin, 4));
        rmin = fminf(rmin, __shfl_xor(rmin, 8));
        rmin = fminf(rmin, __shfl_xor(rmin, 16));
        if (llo32 == 0) pmin[(size_t)row * NSLOT + cslot] = rmin;
      }
    }
  }
#undef RD
#undef PH
}

// ---------------- fallback: reg-staged 128^2 fused GEMM (small ws) ----------------
constexpr int FBM = 128, FBK = 32;
constexpr int FNWG = (NB / FBM) * (NC / FBM);
typedef __attribute__((ext_vector_type(4))) float f32x4;
__global__ __launch_bounds__(256) void gemm_fb_kernel(
    const float* __restrict__ xf, const float* __restrict__ cf,
    const float* __restrict__ xnorm, const float* __restrict__ cnorm,
    const int* __restrict__ labels,
    float* __restrict__ own, float* __restrict__ pmin) {
  __shared__ alignas(16) unsigned short lA[FBM * FBK];
  __shared__ alignas(16) unsigned short lB[FBM * FBK];
  const int tid = threadIdx.x, lane = tid & 63, wid = tid >> 6;
  int bid = blockIdx.x;
  int swz = (bid & 7) * (FNWG >> 3) + (bid >> 3);
  const int brow0 = (swz / (NC / FBM)) * FBM;
  const int bcol0 = (swz % (NC / FBM)) * FBM;
  const int wr = wid >> 1, wc = wid & 1;
  f32x4 acc[4][4];
  #pragma unroll
  for (int m = 0; m < 4; m++)
    #pragma unroll
    for (int n = 0; n < 4; n++) acc[m][n] = (f32x4){0.f, 0.f, 0.f, 0.f};
  for (int k0 = 0; k0 < ND; k0 += FBK) {
    __syncthreads();
    int ar = tid >> 1, ac = (tid & 1) << 4;
    const float* ga = xf + (size_t)(brow0 + ar) * ND + k0 + ac;
    const float* gb = cf + (size_t)(bcol0 + ar) * ND + k0 + ac;
    usvec8 ua[2], ub[2];
    #pragma unroll
    for (int h = 0; h < 2; h++) {
      float4 p = *(const float4*)(ga + h * 8), q = *(const float4*)(ga + h * 8 + 4);
      ua[h][0] = f2bf(p.x); ua[h][1] = f2bf(p.y); ua[h][2] = f2bf(p.z); ua[h][3] = f2bf(p.w);
      ua[h][4] = f2bf(q.x); ua[h][5] = f2bf(q.y); ua[h][6] = f2bf(q.z); ua[h][7] = f2bf(q.w);
      float4 r = *(const float4*)(gb + h * 8), s = *(const float4*)(gb + h * 8 + 4);
      ub[h][0] = f2bf(r.x); ub[h][1] = f2bf(r.y); ub[h][2] = f2bf(r.z); ub[h][3] = f2bf(r.w);
      ub[h][4] = f2bf(s.x); ub[h][5] = f2bf(s.y); ub[h][6] = f2bf(s.z); ub[h][7] = f2bf(s.w);
    }
    *(usvec8*)&lA[ar * FBK + ac] = ua[0];
    *(usvec8*)&lA[ar * FBK + ac + 8] = ua[1];
    *(usvec8*)&lB[ar * FBK + ac] = ub[0];
    *(usvec8*)&lB[ar * FBK + ac + 8] = ub[1];
    __syncthreads();
    bf16x8 af[4], bf[4];
    #pragma unroll
    for (int m = 0; m < 4; m++)
      af[m] = *(const bf16x8*)&lA[(wr * 64 + m * 16 + (lane & 15)) * FBK + (lane >> 4) * 8];
    #pragma unroll
    for (int n = 0; n < 4; n++)
      bf[n] = *(const bf16x8*)&lB[(wc * 64 + n * 16 + (lane & 15)) * FBK + (lane >> 4) * 8];
    #pragma unroll
    for (int m = 0; m < 4; m++)
      #pragma unroll
      for (int n = 0; n < 4; n++)
        acc[m][n] = __builtin_amdgcn_mfma_f32_16x16x32_bf16(af[m], bf[n], acc[m][n], 0, 0, 0);
  }
  const int llo = lane & 15, lhi = lane >> 4;
  float cnr[4];
  int coln[4];
  #pragma unroll
  for (int n = 0; n < 4; n++) {
    coln[n] = bcol0 + wc * 64 + n * 16 + llo;
    cnr[n] = cnorm[coln[n]];
  }
  const int cslot = bcol0 / 64 + wc;
  #pragma unroll
  for (int m = 0; m < 4; m++)
    #pragma unroll
    for (int j = 0; j < 4; j++) {
      int row = brow0 + wr * 64 + m * 16 + lhi * 4 + j;
      float xn = xnorm[row];
      int lbl = labels[row];
      float rmin = 1e38f;
      #pragma unroll
      for (int n = 0; n < 4; n++) {
        float d = xn + cnr[n] - 2.0f * acc[m][n][j];
        if (coln[n] == lbl) own[row] = d;
        else rmin = fminf(rmin, d);
      }
      rmin = fminf(rmin, __shfl_xor(rmin, 1));
      rmin = fminf(rmin, __shfl_xor(rmin, 2));
      rmin = fminf(rmin, __shfl_xor(rmin, 4));
      rmin = fminf(rmin, __shfl_xor(rmin, 8));
      if (llo == 0) pmin[(size_t)row * NSLOT + cslot] = rmin;
    }
}

// ---------------- final: hinge + deterministic sum ----------------
__global__ __launch_bounds__(256) void finalize_kernel(const float* __restrict__ own,
                                                       const float* __restrict__ pmin,
                                                       const float* __restrict__ margin,
                                                       const float* __restrict__ wgt,
                                                       float* __restrict__ partial) {
  int r = blockIdx.x * 256 + threadIdx.x;
  const float4* p4 = (const float4*)(pmin + (size_t)r * NSLOT);
  float mn = 1e38f;
  #pragma unroll
  for (int i = 0; i < NSLOT / 4; i++) {
    float4 v = p4[i];
    mn = fminf(mn, fminf(fminf(v.x, v.y), fminf(v.z, v.w)));
  }
  float W = *wgt;
  float h = fmaxf(*margin + W * own[r] - (1.0f - W) * mn, 0.0f);
  #pragma unroll
  for (int m = 1; m < 64; m <<= 1) h += __shfl_xor(h, m);
  __shared__ float red[4];
  int lane = threadIdx.x & 63, wid = threadIdx.x >> 6;
  if (lane == 0) red[wid] = h;
  __syncthreads();
  if (threadIdx.x == 0) partial[blockIdx.x] = red[0] + red[1] + red[2] + red[3];
}

__global__ void final2_kernel(const float* __restrict__ partial, float* __restrict__ out) {
  float s = (threadIdx.x < NB / 256) ? partial[threadIdx.x] : 0.f;
  #pragma unroll
  for (int m = 1; m < 64; m <<= 1) s += __shfl_xor(s, m);
  if (threadIdx.x == 0) out[0] = s * (1.0f / NB);
}

extern "C" void kernel_launch(void* const* d_in, const int* in_sizes, int n_in,
                              void* d_out, int out_size, void* d_ws, size_t ws_size,
                              hipStream_t stream) {
  const float* x = (const float*)d_in[0];
  const float* cen = (const float*)d_in[1];
  const int* labels = (const int*)d_in[2];
  const float* margin = (const float*)d_in[3];
  const float* wgt = (const float*)d_in[4];
  float* out = (float*)d_out;

  char* base = (char*)d_ws;
  size_t off = 0;
  auto alloc = [&](size_t bytes) {
    void* q = base + off;
    off = (off + bytes + 255) & ~(size_t)255;
    return q;
  };
  float* xnorm = (float*)alloc((size_t)NB * 4);
  float* cnorm = (float*)alloc((size_t)NC * 4);
  float* own = (float*)alloc((size_t)NB * 4);
  float* pmin = (float*)alloc((size_t)NB * NSLOT * 4);
  float* partial = (float*)alloc(64 * 4);
  unsigned short* xb = (unsigned short*)alloc((size_t)NB * ND * 2);
  unsigned short* cb = (unsigned short*)alloc((size_t)NC * ND * 2);
  size_t need_big = off;  // ~52.9 MB

  if (ws_size >= need_big) {
    prep_kernel<<<NB + NC, 256, 0, stream>>>(x, cen, xnorm, cnorm, xb, cb);
    gemm8_kernel<<<NWG, 512, 0, stream>>>(xb, cb, xnorm, cnorm, labels, own, pmin);
  } else {
    norms_kernel<<<NB + NC, 256, 0, stream>>>(x, cen, xnorm, cnorm);
    gemm_fb_kernel<<<FNWG, 256, 0, stream>>>(x, cen, xnorm, cnorm, labels, own, pmin);
  }
  finalize_kernel<<<NB / 256, 256, 0, stream>>>(own, pmin, margin, wgt, partial);
  final2_kernel<<<1, 64, 0, stream>>>(partial, out);
}

// Round 9
// 177.073 us; speedup vs baseline: 1.0051x; 1.0051x over previous
//
#include <hip/hip_runtime.h>
#include <hip/hip_bf16.h>
#include <cstdint>

// TripCenterLoss_min_margin: B=8192, C=4096, D=2048
// loss = mean_b max(margin + w*dist_own(b) - (1-w)*min_{c!=lbl} dist(b,c), 0)
constexpr int NB = 8192;
constexpr int NC = 4096;
constexpr int ND = 2048;

// ---- prefetch-pipelined 256x256 GEMM, 32x32x16 MFMA, asm counted-lgkm ----
constexpr int BM = 256, BN = 256, BK = 64;
constexpr int NRB = NB / BM;    // 32
constexpr int NCB = NC / BN;    // 16
constexpr int NWG = NRB * NCB;  // 512  (%8==0 -> bijective XCD swizzle)
constexpr int NT = ND / BK;     // 32 K-tiles
constexpr int NIT = NT / 2;     // 16 iterations (2 K-tiles each)
constexpr int NSLOT = NC / 64;  // 64 pmin slots per row

typedef __attribute__((ext_vector_type(8))) __bf16 bf16x8;
typedef __attribute__((ext_vector_type(8))) unsigned short usvec8;
typedef __attribute__((ext_vector_type(4))) unsigned short usvec4;
typedef __attribute__((ext_vector_type(16))) float f32x16;

__device__ inline unsigned short f2bf(float f) {
  unsigned int u = __float_as_uint(f);
  u += 0x7fffu + ((u >> 16) & 1u);  // RNE
  return (unsigned short)(u >> 16);
}

// ---------------- fused norms + f32->bf16 convert ----------------
__global__ __launch_bounds__(256) void prep_kernel(const float* __restrict__ x,
                                                   const float* __restrict__ cen,
                                                   float* __restrict__ xnorm,
                                                   float* __restrict__ cnorm,
                                                   unsigned short* __restrict__ xb,
                                                   unsigned short* __restrict__ cb) {
  int row = blockIdx.x;
  const float* src;
  float* ndst;
  unsigned short* bdst;
  if (row < NB) { src = x + (size_t)row * ND; ndst = xnorm + row; bdst = xb + (size_t)row * ND; }
  else { row -= NB; src = cen + (size_t)row * ND; ndst = cnorm + row; bdst = cb + (size_t)row * ND; }
  float s = 0.f;
  #pragma unroll
  for (int it = 0; it < 2; it++) {
    int i = threadIdx.x * 4 + it * 1024;
    float4 v = *(const float4*)(src + i);
    s += v.x * v.x + v.y * v.y + v.z * v.z + v.w * v.w;
    usvec4 u;
    u[0] = f2bf(v.x); u[1] = f2bf(v.y); u[2] = f2bf(v.z); u[3] = f2bf(v.w);
    *(usvec4*)(bdst + i) = u;
  }
  #pragma unroll
  for (int m = 1; m < 64; m <<= 1) s += __shfl_xor(s, m);
  __shared__ float red[4];
  int lane = threadIdx.x & 63, wid = threadIdx.x >> 6;
  if (lane == 0) red[wid] = s;
  __syncthreads();
  if (threadIdx.x == 0) *ndst = red[0] + red[1] + red[2] + red[3];
}

// ---------------- norms only (fallback path) ----------------
__global__ __launch_bounds__(256) void norms_kernel(const float* __restrict__ x,
                                                    const float* __restrict__ cen,
                                                    float* __restrict__ xnorm,
                                                    float* __restrict__ cnorm) {
  int row = blockIdx.x;
  const float* src;
  float* dst;
  if (row < NB) { src = x + (size_t)row * ND; dst = xnorm + row; }
  else          { src = cen + (size_t)(row - NB) * ND; dst = cnorm + (row - NB); }
  float s = 0.f;
  #pragma unroll
  for (int it = 0; it < 2; it++) {
    int i = threadIdx.x * 4 + it * 1024;
    float4 v = *(const float4*)(src + i);
    s += v.x * v.x + v.y * v.y + v.z * v.z + v.w * v.w;
  }
  #pragma unroll
  for (int m = 1; m < 64; m <<= 1) s += __shfl_xor(s, m);
  __shared__ float red[4];
  int lane = threadIdx.x & 63, wid = threadIdx.x >> 6;
  if (lane == 0) red[wid] = s;
  __syncthreads();
  if (threadIdx.x == 0) *dst = red[0] + red[1] + red[2] + red[3];
}

// ---------------- async global->LDS ----------------
__device__ inline void gload_lds16(const void* g, void* lds) {
  __builtin_amdgcn_global_load_lds(
      (const __attribute__((address_space(1))) unsigned int*)g,
      (__attribute__((address_space(3))) unsigned int*)lds, 16, 0, 0);
}

// Stage one half-tile (256 rows x 32 k, 16KB) into a contiguous LDS region.
// LINEAR LDS dest; XOR swizzle applied by permuting the GLOBAL source
// (involution, rule 21): physical chunk pc = kc ^ ((row>>1)&3).
// R4-verified: 0 bank conflicts on the swizzled ds_read_b128 pattern.
__device__ __forceinline__ void stage_half(unsigned short* reg, const unsigned short* gsrc,
                                           int row0, int kcol0, int wid, int lane) {
  #pragma unroll
  for (int i = 0; i < 2; i++) {
    int c = (wid * 2 + i) * 64 + lane;        // chunk index 0..1023
    int row = c >> 2;                         // 4 chunks (64B) per row
    int kc = (c & 3) ^ ((row >> 1) & 3);      // logical k-chunk at this physical slot
    gload_lds16(gsrc + (size_t)(row0 + row) * ND + kcol0 + kc * 8,
                (char*)reg + (size_t)c * 16);
  }
}

// ---------------- prefetch-pipelined 256^2 fused GEMM (32x32x16) ----------------
// 8 phases/iter (2 K-tiles); phase = one K-step of 16.
// Phase p: barrier | issue 6 OPAQUE asm ds_read_b128 for frags(p+1) +
//          1 stage_half | asm lgkmcnt(6) (waits ONLY the 6 old reads; the 6
//          new drain UNDER the MFMA cluster) | sched_barrier (rule 18) |
//          setprio(1) | 8 MFMA frags(p) | setprio(0) | [vmcnt(6) odd phases].
// The asm reads are invisible to the compiler's waitcnt pass -> it cannot
// insert a serializing lgkmcnt(0); the counted wait is ours (T3/T4, m218).
//
// Region/vmcnt ledger: identical to R8 (ref-verified absmax 0.0):
//   p0:(1,B,kh1)@t+1   p1:(0,A,kh0)@t+2   p2:(0,B,kh0)@t+2  p3:(0,A,kh1)@t+2
//   p4:(0,B,kh1)@t+2   p5:(1,A,kh0)@t+3   p6:(1,B,kh0)@t+3  p7:(1,A,kh1)@t+3
// vmcnt(6) at p1/p3/p5/p7 keeps 3 stages in flight; every region is read
// >=5 phases after staging, covered by an interposed vmcnt + barrier.
// Stage-target stability: region staged at p was last prefetch-read at p-2;
// those reads are the "oldest 6" retired by p-1's lgkmcnt(6), and p's top
// barrier orders all waves' retirement before the DMA issue.
__global__ __launch_bounds__(512, 2) void gemm8_kernel(
    const unsigned short* __restrict__ xb, const unsigned short* __restrict__ cb,
    const float* __restrict__ xnorm, const float* __restrict__ cnorm,
    const int* __restrict__ labels,
    float* __restrict__ own, float* __restrict__ pmin) {
  // [buf][mat A=0/B=1][khalf][256 rows x 32 k]; 128 KiB total.
  __shared__ unsigned short lds[2][2][2][256 * 32];

  const int tid = threadIdx.x;
  const int lane = tid & 63;
  const int wid = tid >> 6;
  const int llo32 = lane & 31;
  const int hi = lane >> 5;
  // un-swizzle on read (32x32 frag: row = lane&31, kc = 2*ks + hi):
  // phys chunk = (2ks+hi) ^ rx, rx = (row>>1)&3; applied as a VALUE in the
  // precomputed per-thread base (not an address XOR).
  const int rx = (llo32 >> 1) & 3;
  const unsigned swk0 = (unsigned)((hi ^ rx) << 4);
  const unsigned swk1 = swk0 ^ 32u;

  // LDS integer base (AS3 pointer value == LDS byte offset)
  const unsigned lbase = (unsigned)(unsigned long long)
      (__attribute__((address_space(3))) const char*)&lds[0][0][0][0];
  const unsigned pA0 = lbase + (unsigned)((wid >> 2) * 128 + llo32) * 64u + swk0;
  const unsigned pA1 = lbase + (unsigned)((wid >> 2) * 128 + llo32) * 64u + swk1;
  const unsigned pB0 = lbase + (unsigned)((wid & 3) * 64 + llo32) * 64u + swk0;
  const unsigned pB1 = lbase + (unsigned)((wid & 3) * 64 + llo32) * 64u + swk1;

  int bid = blockIdx.x;
  int swz = (bid & 7) * (NWG / 8) + (bid >> 3);
  const int brow0 = (swz / NCB) * BM;
  const int bcol0 = (swz % NCB) * BN;
  const int wr = wid >> 2, wc = wid & 3;  // 2x4 wave grid: wave output 128x64

  f32x16 acc[4][2];
  #pragma unroll
  for (int m = 0; m < 4; m++)
    #pragma unroll
    for (int n = 0; n < 2; n++)
      acc[m][n] = (f32x16)(0.f);

  bf16x8 fa0[4], fb0[2], fa1[4], fb1[2];

// 6 opaque volatile asm ds_read_b128 (4 A + 2 B) for (BUF, KH, KS).
// Region offset = ((BUF)*4 + mat*2 + KH)*16384; frag stride = 32 rows = 2048B.
#define RD_ASM(FA, FB, BUF, KH, KS)                                              \
  {                                                                              \
    unsigned ra = ((BUF) * 4u + (KH)) * 16384u + ((KS) ? pA1 : pA0);             \
    unsigned rb = ((BUF) * 4u + 2u + (KH)) * 16384u + ((KS) ? pB1 : pB0);        \
    asm volatile("ds_read_b128 %0, %1"             : "=v"(FA[0]) : "v"(ra));     \
    asm volatile("ds_read_b128 %0, %1 offset:2048" : "=v"(FA[1]) : "v"(ra));     \
    asm volatile("ds_read_b128 %0, %1 offset:4096" : "=v"(FA[2]) : "v"(ra));     \
    asm volatile("ds_read_b128 %0, %1 offset:6144" : "=v"(FA[3]) : "v"(ra));     \
    asm volatile("ds_read_b128 %0, %1"             : "=v"(FB[0]) : "v"(rb));     \
    asm volatile("ds_read_b128 %0, %1 offset:2048" : "=v"(FB[1]) : "v"(rb));     \
  }

// phase: barrier | prefetch-read frags(p+1) + stage | lgkm(6) | MFMA frags(p)
#define PH(FAc, FBc, FAn, FBn, NBUF, NKH, NKS, STAGE_STMT, VM_STMT)            \
  {                                                                            \
    __builtin_amdgcn_s_barrier();                                              \
    __builtin_amdgcn_sched_barrier(0);                                         \
    RD_ASM(FAn, FBn, NBUF, NKH, NKS);                                          \
    STAGE_STMT;                                                                \
    asm volatile("s_waitcnt lgkmcnt(6)" ::: "memory");                         \
    __builtin_amdgcn_sched_barrier(0);                                         \
    __builtin_amdgcn_s_setprio(1);                                             \
    _Pragma("unroll") for (int m = 0; m < 4; m++)                              \
      _Pragma("unroll") for (int n = 0; n < 2; n++)                            \
        acc[m][n] = __builtin_amdgcn_mfma_f32_32x32x16_bf16(FAc[m], FBc[n],    \
                                                            acc[m][n], 0, 0, 0); \
    __builtin_amdgcn_s_setprio(0);                                             \
    __builtin_amdgcn_sched_barrier(0);                                         \
    VM_STMT;                                                                   \
  }

  // prologue: t0 {A.kh0,B.kh0,A.kh1,B.kh1}, t1 {A.kh0,B.kh0,A.kh1} = 14 loads;
  // vmcnt(6) -> all of t0 landed; outstanding = t1's 3 stages (6 loads).
  stage_half(&lds[0][0][0][0], xb, brow0, 0, wid, lane);
  stage_half(&lds[0][1][0][0], cb, bcol0, 0, wid, lane);
  stage_half(&lds[0][0][1][0], xb, brow0, 32, wid, lane);
  stage_half(&lds[0][1][1][0], cb, bcol0, 32, wid, lane);
  stage_half(&lds[1][0][0][0], xb, brow0, 64, wid, lane);
  stage_half(&lds[1][1][0][0], cb, bcol0, 64, wid, lane);
  stage_half(&lds[1][0][1][0], xb, brow0, 96, wid, lane);
  asm volatile("s_waitcnt vmcnt(6)" ::: "memory");
  __builtin_amdgcn_s_barrier();
  __builtin_amdgcn_sched_barrier(0);
  RD_ASM(fa0, fb0, 0, 0, 0);  // frags(p0): 6 outstanding entering the loop

  for (int it = 0; it < NIT - 1; ++it) {
    const int t = 2 * it;
    const int k1 = (t + 1) * BK, k2 = (t + 2) * BK, k3 = (t + 3) * BK;
    PH(fa0, fb0, fa1, fb1, 0, 0, 1,
       stage_half(&lds[1][1][1][0], cb, bcol0, k1 + 32, wid, lane), (void)0)
    PH(fa1, fb1, fa0, fb0, 0, 1, 0,
       stage_half(&lds[0][0][0][0], xb, brow0, k2, wid, lane),
       asm volatile("s_waitcnt vmcnt(6)" ::: "memory"))
    PH(fa0, fb0, fa1, fb1, 0, 1, 1,
       stage_half(&lds[0][1][0][0], cb, bcol0, k2, wid, lane), (void)0)
    PH(fa1, fb1, fa0, fb0, 1, 0, 0,
       stage_half(&lds[0][0][1][0], xb, brow0, k2 + 32, wid, lane),
       asm volatile("s_waitcnt vmcnt(6)" ::: "memory"))
    PH(fa0, fb0, fa1, fb1, 1, 0, 1,
       stage_half(&lds[0][1][1][0], cb, bcol0, k2 + 32, wid, lane), (void)0)
    PH(fa1, fb1, fa0, fb0, 1, 1, 0,
       stage_half(&lds[1][0][0][0], xb, brow0, k3, wid, lane),
       asm volatile("s_waitcnt vmcnt(6)" ::: "memory"))
    PH(fa0, fb0, fa1, fb1, 1, 1, 1,
       stage_half(&lds[1][1][0][0], cb, bcol0, k3, wid, lane), (void)0)
    PH(fa1, fb1, fa0, fb0, 0, 0, 0,
       stage_half(&lds[1][0][1][0], xb, brow0, k3 + 32, wid, lane),
       asm volatile("s_waitcnt vmcnt(6)" ::: "memory"))
  }
  // tail iter (t=30,31): only (1,B,kh1)@t31 left to stage; vmcnt(0) at p3.
  {
    const int k1 = (NT - 1) * BK;
    PH(fa0, fb0, fa1, fb1, 0, 0, 1,
       stage_half(&lds[1][1][1][0], cb, bcol0, k1 + 32, wid, lane), (void)0)
    PH(fa1, fb1, fa0, fb0, 0, 1, 0, (void)0,
       asm volatile("s_waitcnt vmcnt(6)" ::: "memory"))
    PH(fa0, fb0, fa1, fb1, 0, 1, 1, (void)0, (void)0)
    PH(fa1, fb1, fa0, fb0, 1, 0, 0, (void)0,
       asm volatile("s_waitcnt vmcnt(0)" ::: "memory"))
    PH(fa0, fb0, fa1, fb1, 1, 0, 1, (void)0, (void)0)
    PH(fa1, fb1, fa0, fb0, 1, 1, 0, (void)0, (void)0)
    PH(fa0, fb0, fa1, fb1, 1, 1, 1, (void)0, (void)0)
    // final cluster: no new reads -> full drain of the last 6 (rule 18)
    asm volatile("s_waitcnt lgkmcnt(0)" ::: "memory");
    __builtin_amdgcn_sched_barrier(0);
    __builtin_amdgcn_s_setprio(1);
    #pragma unroll
    for (int m = 0; m < 4; m++)
      #pragma unroll
      for (int n = 0; n < 2; n++)
        acc[m][n] = __builtin_amdgcn_mfma_f32_32x32x16_bf16(fa1[m], fb1[n],
                                                            acc[m][n], 0, 0, 0);
    __builtin_amdgcn_s_setprio(0);
  }

  // ---- epilogue: dist = xn + cn - 2*dot; own-col; per-row min ----
  // 32x32 C/D layout (m74/m101-verified): col = lane&31,
  // row = (reg&3) + 8*(reg>>2) + 4*(lane>>5), reg in [0,16)
  const int col0 = bcol0 + wc * 64 + llo32;
  const int col1 = col0 + 32;
  const float cn0 = cnorm[col0];
  const float cn1 = cnorm[col1];
  const int cslot = bcol0 / 64 + wc;
  #pragma unroll
  for (int m = 0; m < 4; m++) {
    #pragma unroll
    for (int g = 0; g < 4; g++) {
      const int r0 = brow0 + wr * 128 + m * 32 + hi * 4 + g * 8;
      float4 xn4 = *(const float4*)(xnorm + r0);
      int4 lb4 = *(const int4*)(labels + r0);
      #pragma unroll
      for (int j = 0; j < 4; j++) {
        const int reg = g * 4 + j;
        const int row = r0 + j;
        const float xnv = (j == 0) ? xn4.x : (j == 1) ? xn4.y : (j == 2) ? xn4.z : xn4.w;
        const int lbl = (j == 0) ? lb4.x : (j == 1) ? lb4.y : (j == 2) ? lb4.z : lb4.w;
        float d0 = xnv + cn0 - 2.0f * acc[m][0][reg];
        float d1 = xnv + cn1 - 2.0f * acc[m][1][reg];
        float rmin = 1e38f;
        if (col0 == lbl) own[row] = d0; else rmin = d0;
        if (col1 == lbl) own[row] = d1; else rmin = fminf(rmin, d1);
        rmin = fminf(rmin, __shfl_xor(rmin, 1));
        rmin = fminf(rmin, __shfl_xor(rmin, 2));
        rmin = fminf(rmin, __shfl_xor(rmin, 4));
        rmin = fminf(rmin, __shfl_xor(rmin, 8));
        rmin = fminf(rmin, __shfl_xor(rmin, 16));
        if (llo32 == 0) pmin[(size_t)row * NSLOT + cslot] = rmin;
      }
    }
  }
#undef RD_ASM
#undef PH
}

// ---------------- fallback: reg-staged 128^2 fused GEMM (small ws) ----------------
constexpr int FBM = 128, FBK = 32;
constexpr int FNWG = (NB / FBM) * (NC / FBM);
typedef __attribute__((ext_vector_type(4))) float f32x4;
__global__ __launch_bounds__(256) void gemm_fb_kernel(
    const float* __restrict__ xf, const float* __restrict__ cf,
    const float* __restrict__ xnorm, const float* __restrict__ cnorm,
    const int* __restrict__ labels,
    float* __restrict__ own, float* __restrict__ pmin) {
  __shared__ alignas(16) unsigned short lA[FBM * FBK];
  __shared__ alignas(16) unsigned short lB[FBM * FBK];
  const int tid = threadIdx.x, lane = tid & 63, wid = tid >> 6;
  int bid = blockIdx.x;
  int swz = (bid & 7) * (FNWG >> 3) + (bid >> 3);
  const int brow0 = (swz / (NC / FBM)) * FBM;
  const int bcol0 = (swz % (NC / FBM)) * FBM;
  const int wr = wid >> 1, wc = wid & 1;
  f32x4 acc[4][4];
  #pragma unroll
  for (int m = 0; m < 4; m++)
    #pragma unroll
    for (int n = 0; n < 4; n++) acc[m][n] = (f32x4){0.f, 0.f, 0.f, 0.f};
  for (int k0 = 0; k0 < ND; k0 += FBK) {
    __syncthreads();
    int ar = tid >> 1, ac = (tid & 1) << 4;
    const float* ga = xf + (size_t)(brow0 + ar) * ND + k0 + ac;
    const float* gb = cf + (size_t)(bcol0 + ar) * ND + k0 + ac;
    usvec8 ua[2], ub[2];
    #pragma unroll
    for (int h = 0; h < 2; h++) {
      float4 p = *(const float4*)(ga + h * 8), q = *(const float4*)(ga + h * 8 + 4);
      ua[h][0] = f2bf(p.x); ua[h][1] = f2bf(p.y); ua[h][2] = f2bf(p.z); ua[h][3] = f2bf(p.w);
      ua[h][4] = f2bf(q.x); ua[h][5] = f2bf(q.y); ua[h][6] = f2bf(q.z); ua[h][7] = f2bf(q.w);
      float4 r = *(const float4*)(gb + h * 8), s = *(const float4*)(gb + h * 8 + 4);
      ub[h][0] = f2bf(r.x); ub[h][1] = f2bf(r.y); ub[h][2] = f2bf(r.z); ub[h][3] = f2bf(r.w);
      ub[h][4] = f2bf(s.x); ub[h][5] = f2bf(s.y); ub[h][6] = f2bf(s.z); ub[h][7] = f2bf(s.w);
    }
    *(usvec8*)&lA[ar * FBK + ac] = ua[0];
    *(usvec8*)&lA[ar * FBK + ac + 8] = ua[1];
    *(usvec8*)&lB[ar * FBK + ac] = ub[0];
    *(usvec8*)&lB[ar * FBK + ac + 8] = ub[1];
    __syncthreads();
    bf16x8 af[4], bf[4];
    #pragma unroll
    for (int m = 0; m < 4; m++)
      af[m] = *(const bf16x8*)&lA[(wr * 64 + m * 16 + (lane & 15)) * FBK + (lane >> 4) * 8];
    #pragma unroll
    for (int n = 0; n < 4; n++)
      bf[n] = *(const bf16x8*)&lB[(wc * 64 + n * 16 + (lane & 15)) * FBK + (lane >> 4) * 8];
    #pragma unroll
    for (int m = 0; m < 4; m++)
      #pragma unroll
      for (int n = 0; n < 4; n++)
        acc[m][n] = __builtin_amdgcn_mfma_f32_16x16x32_bf16(af[m], bf[n], acc[m][n], 0, 0, 0);
  }
  const int llo = lane & 15, lhi = lane >> 4;
  float cnr[4];
  int coln[4];
  #pragma unroll
  for (int n = 0; n < 4; n++) {
    coln[n] = bcol0 + wc * 64 + n * 16 + llo;
    cnr[n] = cnorm[coln[n]];
  }
  const int cslot = bcol0 / 64 + wc;
  #pragma unroll
  for (int m = 0; m < 4; m++)
    #pragma unroll
    for (int j = 0; j < 4; j++) {
      int row = brow0 + wr * 64 + m * 16 + lhi * 4 + j;
      float xn = xnorm[row];
      int lbl = labels[row];
      float rmin = 1e38f;
      #pragma unroll
      for (int n = 0; n < 4; n++) {
        float d = xn + cnr[n] - 2.0f * acc[m][n][j];
        if (coln[n] == lbl) own[row] = d;
        else rmin = fminf(rmin, d);
      }
      rmin = fminf(rmin, __shfl_xor(rmin, 1));
      rmin = fminf(rmin, __shfl_xor(rmin, 2));
      rmin = fminf(rmin, __shfl_xor(rmin, 4));
      rmin = fminf(rmin, __shfl_xor(rmin, 8));
      if (llo == 0) pmin[(size_t)row * NSLOT + cslot] = rmin;
    }
}

// ---------------- final: hinge + deterministic sum ----------------
__global__ __launch_bounds__(256) void finalize_kernel(const float* __restrict__ own,
                                                       const float* __restrict__ pmin,
                                                       const float* __restrict__ margin,
                                                       const float* __restrict__ wgt,
                                                       float* __restrict__ partial) {
  int r = blockIdx.x * 256 + threadIdx.x;
  const float4* p4 = (const float4*)(pmin + (size_t)r * NSLOT);
  float mn = 1e38f;
  #pragma unroll
  for (int i = 0; i < NSLOT / 4; i++) {
    float4 v = p4[i];
    mn = fminf(mn, fminf(fminf(v.x, v.y), fminf(v.z, v.w)));
  }
  float W = *wgt;
  float h = fmaxf(*margin + W * own[r] - (1.0f - W) * mn, 0.0f);
  #pragma unroll
  for (int m = 1; m < 64; m <<= 1) h += __shfl_xor(h, m);
  __shared__ float red[4];
  int lane = threadIdx.x & 63, wid = threadIdx.x >> 6;
  if (lane == 0) red[wid] = h;
  __syncthreads();
  if (threadIdx.x == 0) partial[blockIdx.x] = red[0] + red[1] + red[2] + red[3];
}

__global__ void final2_kernel(const float* __restrict__ partial, float* __restrict__ out) {
  float s = (threadIdx.x < NB / 256) ? partial[threadIdx.x] : 0.f;
  #pragma unroll
  for (int m = 1; m < 64; m <<= 1) s += __shfl_xor(s, m);
  if (threadIdx.x == 0) out[0] = s * (1.0f / NB);
}

extern "C" void kernel_launch(void* const* d_in, const int* in_sizes, int n_in,
                              void* d_out, int out_size, void* d_ws, size_t ws_size,
                              hipStream_t stream) {
  const float* x = (const float*)d_in[0];
  const float* cen = (const float*)d_in[1];
  const int* labels = (const int*)d_in[2];
  const float* margin = (const float*)d_in[3];
  const float* wgt = (const float*)d_in[4];
  float* out = (float*)d_out;

  char* base = (char*)d_ws;
  size_t off = 0;
  auto alloc = [&](size_t bytes) {
    void* q = base + off;
    off = (off + bytes + 255) & ~(size_t)255;
    return q;
  };
  float* xnorm = (float*)alloc((size_t)NB * 4);
  float* cnorm = (float*)alloc((size_t)NC * 4);
  float* own = (float*)alloc((size_t)NB * 4);
  float* pmin = (float*)alloc((size_t)NB * NSLOT * 4);
  float* partial = (float*)alloc(64 * 4);
  unsigned short* xb = (unsigned short*)alloc((size_t)NB * ND * 2);
  unsigned short* cb = (unsigned short*)alloc((size_t)NC * ND * 2);
  size_t need_big = off;  // ~52.9 MB

  if (ws_size >= need_big) {
    prep_kernel<<<NB + NC, 256, 0, stream>>>(x, cen, xnorm, cnorm, xb, cb);
    gemm8_kernel<<<NWG, 512, 0, stream>>>(xb, cb, xnorm, cnorm, labels, own, pmin);
  } else {
    norms_kernel<<<NB + NC, 256, 0, stream>>>(x, cen, xnorm, cnorm);
    gemm_fb_kernel<<<FNWG, 256, 0, stream>>>(x, cen, xnorm, cnorm, labels, own, pmin);
  }
  finalize_kernel<<<NB / 256, 256, 0, stream>>>(own, pmin, margin, wgt, partial);
  final2_kernel<<<1, 64, 0, stream>>>(partial, out);
}

// Round 10
// 166.556 us; speedup vs baseline: 1.0686x; 1.0631x over previous
//
#include <hip/hip_runtime.h>
#include <hip/hip_bf16.h>
#include <cstdint>

// TripCenterLoss_min_margin: B=8192, C=4096, D=2048
// loss = mean_b max(margin + w*dist_own(b) - (1-w)*min_{c!=lbl} dist(b,c), 0)
constexpr int NB = 8192;
constexpr int NC = 4096;
constexpr int ND = 2048;

// ---- K-tile-granular 256x256 GEMM, 16x16x32 MFMA, 1 barrier/tile ----
constexpr int BM = 256, BN = 256, BK = 64;
constexpr int NRB = NB / BM;    // 32
constexpr int NCB = NC / BN;    // 16
constexpr int NWG = NRB * NCB;  // 512  (%8==0 -> bijective XCD swizzle)
constexpr int NT = ND / BK;     // 32 K-tiles
constexpr int NSLOT = NC / 64;  // 64 pmin slots per row

typedef __attribute__((ext_vector_type(8))) __bf16 bf16x8;
typedef __attribute__((ext_vector_type(8))) unsigned short usvec8;
typedef __attribute__((ext_vector_type(4))) unsigned short usvec4;
typedef __attribute__((ext_vector_type(4))) float f32x4;

__device__ inline unsigned short f2bf(float f) {
  unsigned int u = __float_as_uint(f);
  u += 0x7fffu + ((u >> 16) & 1u);  // RNE
  return (unsigned short)(u >> 16);
}

// ---------------- fused norms + f32->bf16 convert ----------------
__global__ __launch_bounds__(256) void prep_kernel(const float* __restrict__ x,
                                                   const float* __restrict__ cen,
                                                   float* __restrict__ xnorm,
                                                   float* __restrict__ cnorm,
                                                   unsigned short* __restrict__ xb,
                                                   unsigned short* __restrict__ cb) {
  int row = blockIdx.x;
  const float* src;
  float* ndst;
  unsigned short* bdst;
  if (row < NB) { src = x + (size_t)row * ND; ndst = xnorm + row; bdst = xb + (size_t)row * ND; }
  else { row -= NB; src = cen + (size_t)row * ND; ndst = cnorm + row; bdst = cb + (size_t)row * ND; }
  float s = 0.f;
  #pragma unroll
  for (int it = 0; it < 2; it++) {
    int i = threadIdx.x * 4 + it * 1024;
    float4 v = *(const float4*)(src + i);
    s += v.x * v.x + v.y * v.y + v.z * v.z + v.w * v.w;
    usvec4 u;
    u[0] = f2bf(v.x); u[1] = f2bf(v.y); u[2] = f2bf(v.z); u[3] = f2bf(v.w);
    *(usvec4*)(bdst + i) = u;
  }
  #pragma unroll
  for (int m = 1; m < 64; m <<= 1) s += __shfl_xor(s, m);
  __shared__ float red[4];
  int lane = threadIdx.x & 63, wid = threadIdx.x >> 6;
  if (lane == 0) red[wid] = s;
  __syncthreads();
  if (threadIdx.x == 0) *ndst = red[0] + red[1] + red[2] + red[3];
}

// ---------------- norms only (fallback path) ----------------
__global__ __launch_bounds__(256) void norms_kernel(const float* __restrict__ x,
                                                    const float* __restrict__ cen,
                                                    float* __restrict__ xnorm,
                                                    float* __restrict__ cnorm) {
  int row = blockIdx.x;
  const float* src;
  float* dst;
  if (row < NB) { src = x + (size_t)row * ND; dst = xnorm + row; }
  else          { src = cen + (size_t)(row - NB) * ND; dst = cnorm + (row - NB); }
  float s = 0.f;
  #pragma unroll
  for (int it = 0; it < 2; it++) {
    int i = threadIdx.x * 4 + it * 1024;
    float4 v = *(const float4*)(src + i);
    s += v.x * v.x + v.y * v.y + v.z * v.z + v.w * v.w;
  }
  #pragma unroll
  for (int m = 1; m < 64; m <<= 1) s += __shfl_xor(s, m);
  __shared__ float red[4];
  int lane = threadIdx.x & 63, wid = threadIdx.x >> 6;
  if (lane == 0) red[wid] = s;
  __syncthreads();
  if (threadIdx.x == 0) *dst = red[0] + red[1] + red[2] + red[3];
}

// ---------------- async global->LDS ----------------
__device__ inline void gload_lds16(const void* g, void* lds) {
  __builtin_amdgcn_global_load_lds(
      (const __attribute__((address_space(1))) unsigned int*)g,
      (__attribute__((address_space(3))) unsigned int*)lds, 16, 0, 0);
}

// Stage one half-tile (256 rows x 32 k, 16KB) into a contiguous LDS region.
// LINEAR LDS dest; XOR swizzle applied by permuting the GLOBAL source
// (involution, rule 21): physical chunk pc = kc ^ ((row>>1)&3).
// R4/R7-verified: 0 bank conflicts on the 16x16 swizzled ds_read_b128 pattern.
__device__ __forceinline__ void stage_half(unsigned short* reg, const unsigned short* gsrc,
                                           int row0, int kcol0, int wid, int lane) {
  #pragma unroll
  for (int i = 0; i < 2; i++) {
    int c = (wid * 2 + i) * 64 + lane;        // chunk index 0..1023
    int row = c >> 2;                         // 4 chunks (64B) per row
    int kc = (c & 3) ^ ((row >> 1) & 3);      // logical k-chunk at this physical slot
    gload_lds16(gsrc + (size_t)(row0 + row) * ND + kcol0 + kc * 8,
                (char*)reg + (size_t)c * 16);
  }
}

// ---------------- K-tile-granular 256^2 fused GEMM + row-min ----------------
// Per K-tile t (buf = t&1), ONE barrier + ONE counted vmcnt:
//   s_barrier                       // all waves retired reads of tile t-1
//   issue 8 gload_lds: t+1 -> buf^1 // overwrites t-1's regions: safe (above)
//   vmcnt(8)                        // tile t's 8 gloads (issued at t-1) landed;
//                                   // t+1's 8 stay in flight
//   { 12 asm ds_read_b128 (kh) ; lgkmcnt(0)+sched_barrier (rule 18) ;
//     setprio(1) ; 32 MFMA ; setprio(0) }  x2 khalves
// Between barriers the 2 waves/SIMD free-run: one wave's read burst executes
// on the LDS pipe while the other's MFMA burst occupies the matrix pipe
// (m114 implicit wave-level overlap) -- no extra registers needed.
// Induction on vmcnt(8): at tile t top, outstanding = t's 8 + t+1's 8; wait
// leaves newest 8 -> t's data present before any tile-t read. t=31: vmcnt(0).
__global__ __launch_bounds__(512, 2) void gemm8_kernel(
    const unsigned short* __restrict__ xb, const unsigned short* __restrict__ cb,
    const float* __restrict__ xnorm, const float* __restrict__ cnorm,
    const int* __restrict__ labels,
    float* __restrict__ own, float* __restrict__ pmin) {
  // [buf][mat A=0/B=1][khalf][256 rows x 32 k]; 128 KiB total.
  // Byte offsets: buf*65536 + mat*32768 + kh*16384.
  __shared__ unsigned short lds[2][2][2][256 * 32];

  const int tid = threadIdx.x;
  const int lane = tid & 63;
  const int wid = tid >> 6;
  const int llo = lane & 15;
  const int lkc = lane >> 4;
  // un-swizzle on read (verified 0-conflict): physical chunk = lkc ^ ((row>>1)&3);
  // frag rows are llo + 16*m, and (16m>>1)&3 == 0, so llo alone determines it.
  const int sw = ((lkc ^ ((llo >> 1) & 3)) << 4);

  int bid = blockIdx.x;
  int swz = (bid & 7) * (NWG / 8) + (bid >> 3);
  const int brow0 = (swz / NCB) * BM;
  const int bcol0 = (swz % NCB) * BN;
  const int wr = wid >> 2, wc = wid & 3;  // 2x4 wave grid: wave output 128x64

  // LDS integer base (AS3 pointer value == LDS byte offset)
  const unsigned lbase = (unsigned)(unsigned long long)
      (__attribute__((address_space(3))) const char*)&lds[0][0][0][0];
  const unsigned aoff = (unsigned)((wr * 128 + llo) * 64) + (unsigned)sw;
  const unsigned boff = 32768u + (unsigned)((wc * 64 + llo) * 64) + (unsigned)sw;

  f32x4 acc[8][4];
  #pragma unroll
  for (int m = 0; m < 8; m++)
    #pragma unroll
    for (int n = 0; n < 4; n++)
      acc[m][n] = (f32x4){0.f, 0.f, 0.f, 0.f};

  bf16x8 fa[8], fb[4];

// 12 opaque asm ds_read_b128 for khalf KH of buffer byte-offset BUFB.
// A frag m stride = 16 rows * 64B = 1024; B frag n stride = 1024.
#define RD12(BUFB, KH)                                                         \
  {                                                                            \
    unsigned ab = lbase + (BUFB) + (unsigned)((KH)*16384) + aoff;              \
    unsigned bb = lbase + (BUFB) + (unsigned)((KH)*16384) + boff;              \
    asm volatile("ds_read_b128 %0, %1"             : "=v"(fa[0]) : "v"(ab));   \
    asm volatile("ds_read_b128 %0, %1 offset:1024" : "=v"(fa[1]) : "v"(ab));   \
    asm volatile("ds_read_b128 %0, %1 offset:2048" : "=v"(fa[2]) : "v"(ab));   \
    asm volatile("ds_read_b128 %0, %1 offset:3072" : "=v"(fa[3]) : "v"(ab));   \
    asm volatile("ds_read_b128 %0, %1 offset:4096" : "=v"(fa[4]) : "v"(ab));   \
    asm volatile("ds_read_b128 %0, %1 offset:5120" : "=v"(fa[5]) : "v"(ab));   \
    asm volatile("ds_read_b128 %0, %1 offset:6144" : "=v"(fa[6]) : "v"(ab));   \
    asm volatile("ds_read_b128 %0, %1 offset:7168" : "=v"(fa[7]) : "v"(ab));   \
    asm volatile("ds_read_b128 %0, %1"             : "=v"(fb[0]) : "v"(bb));   \
    asm volatile("ds_read_b128 %0, %1 offset:1024" : "=v"(fb[1]) : "v"(bb));   \
    asm volatile("ds_read_b128 %0, %1 offset:2048" : "=v"(fb[2]) : "v"(bb));   \
    asm volatile("ds_read_b128 %0, %1 offset:3072" : "=v"(fb[3]) : "v"(bb));   \
  }

  // prologue: stage tile 0 -> buf0 (8 gloads/wave)
  stage_half(&lds[0][0][0][0], xb, brow0, 0, wid, lane);
  stage_half(&lds[0][1][0][0], cb, bcol0, 0, wid, lane);
  stage_half(&lds[0][0][1][0], xb, brow0, 32, wid, lane);
  stage_half(&lds[0][1][1][0], cb, bcol0, 32, wid, lane);

  for (int t = 0; t < NT; ++t) {
    const unsigned bufb = (unsigned)(t & 1) << 16;
    __builtin_amdgcn_s_barrier();
    if (t < NT - 1) {
      const int nb = (t + 1) & 1;
      const int k = (t + 1) * BK;
      stage_half(&lds[nb][0][0][0], xb, brow0, k, wid, lane);
      stage_half(&lds[nb][1][0][0], cb, bcol0, k, wid, lane);
      stage_half(&lds[nb][0][1][0], xb, brow0, k + 32, wid, lane);
      stage_half(&lds[nb][1][1][0], cb, bcol0, k + 32, wid, lane);
      asm volatile("s_waitcnt vmcnt(8)" ::: "memory");
    } else {
      asm volatile("s_waitcnt vmcnt(0)" ::: "memory");
    }
    #pragma unroll
    for (int kh = 0; kh < 2; ++kh) {
      RD12(bufb, kh);
      asm volatile("s_waitcnt lgkmcnt(0)" ::: "memory");
      __builtin_amdgcn_sched_barrier(0);
      __builtin_amdgcn_s_setprio(1);
      #pragma unroll
      for (int m = 0; m < 8; m++)
        #pragma unroll
        for (int n = 0; n < 4; n++)
          acc[m][n] = __builtin_amdgcn_mfma_f32_16x16x32_bf16(fa[m], fb[n],
                                                              acc[m][n], 0, 0, 0);
      __builtin_amdgcn_s_setprio(0);
      __builtin_amdgcn_sched_barrier(0);
    }
  }

  // ---- epilogue: dist = xn + cn - 2*dot; own-col; per-row min ----
  // C/D layout: col = lane&15, row = (lane>>4)*4 + reg  (m89-verified)
  float cnr[4];
  int coln[4];
  #pragma unroll
  for (int n = 0; n < 4; n++) {
    coln[n] = bcol0 + wc * 64 + n * 16 + llo;
    cnr[n] = cnorm[coln[n]];
  }
  const int cslot = bcol0 / 64 + wc;
  #pragma unroll
  for (int m = 0; m < 8; m++) {
    #pragma unroll
    for (int j = 0; j < 4; j++) {
      int row = brow0 + wr * 128 + m * 16 + lkc * 4 + j;
      float xn = xnorm[row];
      int lbl = labels[row];
      float rmin = 1e38f;
      #pragma unroll
      for (int n = 0; n < 4; n++) {
        float d = xn + cnr[n] - 2.0f * acc[m][n][j];
        if (coln[n] == lbl) own[row] = d;  // exactly one writer per row
        else rmin = fminf(rmin, d);
      }
      rmin = fminf(rmin, __shfl_xor(rmin, 1));
      rmin = fminf(rmin, __shfl_xor(rmin, 2));
      rmin = fminf(rmin, __shfl_xor(rmin, 4));
      rmin = fminf(rmin, __shfl_xor(rmin, 8));
      if (llo == 0) pmin[(size_t)row * NSLOT + cslot] = rmin;
    }
  }
#undef RD12
}

// ---------------- fallback: reg-staged 128^2 fused GEMM (small ws) ----------------
constexpr int FBM = 128, FBK = 32;
constexpr int FNWG = (NB / FBM) * (NC / FBM);
__global__ __launch_bounds__(256) void gemm_fb_kernel(
    const float* __restrict__ xf, const float* __restrict__ cf,
    const float* __restrict__ xnorm, const float* __restrict__ cnorm,
    const int* __restrict__ labels,
    float* __restrict__ own, float* __restrict__ pmin) {
  __shared__ alignas(16) unsigned short lA[FBM * FBK];
  __shared__ alignas(16) unsigned short lB[FBM * FBK];
  const int tid = threadIdx.x, lane = tid & 63, wid = tid >> 6;
  int bid = blockIdx.x;
  int swz = (bid & 7) * (FNWG >> 3) + (bid >> 3);
  const int brow0 = (swz / (NC / FBM)) * FBM;
  const int bcol0 = (swz % (NC / FBM)) * FBM;
  const int wr = wid >> 1, wc = wid & 1;
  f32x4 acc[4][4];
  #pragma unroll
  for (int m = 0; m < 4; m++)
    #pragma unroll
    for (int n = 0; n < 4; n++) acc[m][n] = (f32x4){0.f, 0.f, 0.f, 0.f};
  for (int k0 = 0; k0 < ND; k0 += FBK) {
    __syncthreads();
    int ar = tid >> 1, ac = (tid & 1) << 4;
    const float* ga = xf + (size_t)(brow0 + ar) * ND + k0 + ac;
    const float* gb = cf + (size_t)(bcol0 + ar) * ND + k0 + ac;
    usvec8 ua[2], ub[2];
    #pragma unroll
    for (int h = 0; h < 2; h++) {
      float4 p = *(const float4*)(ga + h * 8), q = *(const float4*)(ga + h * 8 + 4);
      ua[h][0] = f2bf(p.x); ua[h][1] = f2bf(p.y); ua[h][2] = f2bf(p.z); ua[h][3] = f2bf(p.w);
      ua[h][4] = f2bf(q.x); ua[h][5] = f2bf(q.y); ua[h][6] = f2bf(q.z); ua[h][7] = f2bf(q.w);
      float4 r = *(const float4*)(gb + h * 8), s = *(const float4*)(gb + h * 8 + 4);
      ub[h][0] = f2bf(r.x); ub[h][1] = f2bf(r.y); ub[h][2] = f2bf(r.z); ub[h][3] = f2bf(r.w);
      ub[h][4] = f2bf(s.x); ub[h][5] = f2bf(s.y); ub[h][6] = f2bf(s.z); ub[h][7] = f2bf(s.w);
    }
    *(usvec8*)&lA[ar * FBK + ac] = ua[0];
    *(usvec8*)&lA[ar * FBK + ac + 8] = ua[1];
    *(usvec8*)&lB[ar * FBK + ac] = ub[0];
    *(usvec8*)&lB[ar * FBK + ac + 8] = ub[1];
    __syncthreads();
    bf16x8 af[4], bf[4];
    #pragma unroll
    for (int m = 0; m < 4; m++)
      af[m] = *(const bf16x8*)&lA[(wr * 64 + m * 16 + (lane & 15)) * FBK + (lane >> 4) * 8];
    #pragma unroll
    for (int n = 0; n < 4; n++)
      bf[n] = *(const bf16x8*)&lB[(wc * 64 + n * 16 + (lane & 15)) * FBK + (lane >> 4) * 8];
    #pragma unroll
    for (int m = 0; m < 4; m++)
      #pragma unroll
      for (int n = 0; n < 4; n++)
        acc[m][n] = __builtin_amdgcn_mfma_f32_16x16x32_bf16(af[m], bf[n], acc[m][n], 0, 0, 0);
  }
  const int llo = lane & 15, lhi = lane >> 4;
  float cnr[4];
  int coln[4];
  #pragma unroll
  for (int n = 0; n < 4; n++) {
    coln[n] = bcol0 + wc * 64 + n * 16 + llo;
    cnr[n] = cnorm[coln[n]];
  }
  const int cslot = bcol0 / 64 + wc;
  #pragma unroll
  for (int m = 0; m < 4; m++)
    #pragma unroll
    for (int j = 0; j < 4; j++) {
      int row = brow0 + wr * 64 + m * 16 + lhi * 4 + j;
      float xn = xnorm[row];
      int lbl = labels[row];
      float rmin = 1e38f;
      #pragma unroll
      for (int n = 0; n < 4; n++) {
        float d = xn + cnr[n] - 2.0f * acc[m][n][j];
        if (coln[n] == lbl) own[row] = d;
        else rmin = fminf(rmin, d);
      }
      rmin = fminf(rmin, __shfl_xor(rmin, 1));
      rmin = fminf(rmin, __shfl_xor(rmin, 2));
      rmin = fminf(rmin, __shfl_xor(rmin, 4));
      rmin = fminf(rmin, __shfl_xor(rmin, 8));
      if (llo == 0) pmin[(size_t)row * NSLOT + cslot] = rmin;
    }
}

// ---------------- final: hinge + deterministic sum ----------------
__global__ __launch_bounds__(256) void finalize_kernel(const float* __restrict__ own,
                                                       const float* __restrict__ pmin,
                                                       const float* __restrict__ margin,
                                                       const float* __restrict__ wgt,
                                                       float* __restrict__ partial) {
  int r = blockIdx.x * 256 + threadIdx.x;
  const float4* p4 = (const float4*)(pmin + (size_t)r * NSLOT);
  float mn = 1e38f;
  #pragma unroll
  for (int i = 0; i < NSLOT / 4; i++) {
    float4 v = p4[i];
    mn = fminf(mn, fminf(fminf(v.x, v.y), fminf(v.z, v.w)));
  }
  float W = *wgt;
  float h = fmaxf(*margin + W * own[r] - (1.0f - W) * mn, 0.0f);
  #pragma unroll
  for (int m = 1; m < 64; m <<= 1) h += __shfl_xor(h, m);
  __shared__ float red[4];
  int lane = threadIdx.x & 63, wid = threadIdx.x >> 6;
  if (lane == 0) red[wid] = h;
  __syncthreads();
  if (threadIdx.x == 0) partial[blockIdx.x] = red[0] + red[1] + red[2] + red[3];
}

__global__ void final2_kernel(const float* __restrict__ partial, float* __restrict__ out) {
  float s = (threadIdx.x < NB / 256) ? partial[threadIdx.x] : 0.f;
  #pragma unroll
  for (int m = 1; m < 64; m <<= 1) s += __shfl_xor(s, m);
  if (threadIdx.x == 0) out[0] = s * (1.0f / NB);
}

extern "C" void kernel_launch(void* const* d_in, const int* in_sizes, int n_in,
                              void* d_out, int out_size, void* d_ws, size_t ws_size,
                              hipStream_t stream) {
  const float* x = (const float*)d_in[0];
  const float* cen = (const float*)d_in[1];
  const int* labels = (const int*)d_in[2];
  const float* margin = (const float*)d_in[3];
  const float* wgt = (const float*)d_in[4];
  float* out = (float*)d_out;

  char* base = (char*)d_ws;
  size_t off = 0;
  auto alloc = [&](size_t bytes) {
    void* q = base + off;
    off = (off + bytes + 255) & ~(size_t)255;
    return q;
  };
  float* xnorm = (float*)alloc((size_t)NB * 4);
  float* cnorm = (float*)alloc((size_t)NC * 4);
  float* own = (float*)alloc((size_t)NB * 4);
  float* pmin = (float*)alloc((size_t)NB * NSLOT * 4);
  float* partial = (float*)alloc(64 * 4);
  unsigned short* xb = (unsigned short*)alloc((size_t)NB * ND * 2);
  unsigned short* cb = (unsigned short*)alloc((size_t)NC * ND * 2);
  size_t need_big = off;  // ~52.9 MB

  if (ws_size >= need_big) {
    prep_kernel<<<NB + NC, 256, 0, stream>>>(x, cen, xnorm, cnorm, xb, cb);
    gemm8_kernel<<<NWG, 512, 0, stream>>>(xb, cb, xnorm, cnorm, labels, own, pmin);
  } else {
    norms_kernel<<<NB + NC, 256, 0, stream>>>(x, cen, xnorm, cnorm);
    gemm_fb_kernel<<<FNWG, 256, 0, stream>>>(x, cen, xnorm, cnorm, labels, own, pmin);
  }
  finalize_kernel<<<NB / 256, 256, 0, stream>>>(own, pmin, margin, wgt, partial);
  final2_kernel<<<1, 64, 0, stream>>>(partial, out);
}

// Round 11
// 159.844 us; speedup vs baseline: 1.1135x; 1.0420x over previous
//
#include <hip/hip_runtime.h>
#include <hip/hip_bf16.h>
#include <cstdint>

// TripCenterLoss_min_margin: B=8192, C=4096, D=2048
// loss = mean_b max(margin + w*dist_own(b) - (1-w)*min_{c!=lbl} dist(b,c), 0)
constexpr int NB = 8192;
constexpr int NC = 4096;
constexpr int ND = 2048;

// ---- 8-phase 256x256 GEMM (R7 schedule, UNFENCED MFMA clusters) ----
constexpr int BM = 256, BN = 256, BK = 64;
constexpr int NRB = NB / BM;    // 32
constexpr int NCB = NC / BN;    // 16
constexpr int NWG = NRB * NCB;  // 512  (%8==0 -> bijective XCD swizzle)
constexpr int NT = ND / BK;     // 32 K-tiles
constexpr int NIT = NT / 2;     // 16 iterations (2 K-tiles each)
constexpr int NSLOT = NC / 64;  // 64 pmin slots per row

typedef __attribute__((ext_vector_type(8))) __bf16 bf16x8;
typedef __attribute__((ext_vector_type(8))) unsigned short usvec8;
typedef __attribute__((ext_vector_type(4))) unsigned short usvec4;
typedef __attribute__((ext_vector_type(4))) float f32x4;

__device__ inline unsigned short f2bf(float f) {
  unsigned int u = __float_as_uint(f);
  u += 0x7fffu + ((u >> 16) & 1u);  // RNE
  return (unsigned short)(u >> 16);
}

// ---------------- fused norms + f32->bf16 convert ----------------
__global__ __launch_bounds__(256) void prep_kernel(const float* __restrict__ x,
                                                   const float* __restrict__ cen,
                                                   float* __restrict__ xnorm,
                                                   float* __restrict__ cnorm,
                                                   unsigned short* __restrict__ xb,
                                                   unsigned short* __restrict__ cb) {
  int row = blockIdx.x;
  const float* src;
  float* ndst;
  unsigned short* bdst;
  if (row < NB) { src = x + (size_t)row * ND; ndst = xnorm + row; bdst = xb + (size_t)row * ND; }
  else { row -= NB; src = cen + (size_t)row * ND; ndst = cnorm + row; bdst = cb + (size_t)row * ND; }
  float s = 0.f;
  #pragma unroll
  for (int it = 0; it < 2; it++) {
    int i = threadIdx.x * 4 + it * 1024;
    float4 v = *(const float4*)(src + i);
    s += v.x * v.x + v.y * v.y + v.z * v.z + v.w * v.w;
    usvec4 u;
    u[0] = f2bf(v.x); u[1] = f2bf(v.y); u[2] = f2bf(v.z); u[3] = f2bf(v.w);
    *(usvec4*)(bdst + i) = u;
  }
  #pragma unroll
  for (int m = 1; m < 64; m <<= 1) s += __shfl_xor(s, m);
  __shared__ float red[4];
  int lane = threadIdx.x & 63, wid = threadIdx.x >> 6;
  if (lane == 0) red[wid] = s;
  __syncthreads();
  if (threadIdx.x == 0) *ndst = red[0] + red[1] + red[2] + red[3];
}

// ---------------- norms only (fallback path) ----------------
__global__ __launch_bounds__(256) void norms_kernel(const float* __restrict__ x,
                                                    const float* __restrict__ cen,
                                                    float* __restrict__ xnorm,
                                                    float* __restrict__ cnorm) {
  int row = blockIdx.x;
  const float* src;
  float* dst;
  if (row < NB) { src = x + (size_t)row * ND; dst = xnorm + row; }
  else          { src = cen + (size_t)(row - NB) * ND; dst = cnorm + (row - NB); }
  float s = 0.f;
  #pragma unroll
  for (int it = 0; it < 2; it++) {
    int i = threadIdx.x * 4 + it * 1024;
    float4 v = *(const float4*)(src + i);
    s += v.x * v.x + v.y * v.y + v.z * v.z + v.w * v.w;
  }
  #pragma unroll
  for (int m = 1; m < 64; m <<= 1) s += __shfl_xor(s, m);
  __shared__ float red[4];
  int lane = threadIdx.x & 63, wid = threadIdx.x >> 6;
  if (lane == 0) red[wid] = s;
  __syncthreads();
  if (threadIdx.x == 0) *dst = red[0] + red[1] + red[2] + red[3];
}

// ---------------- async global->LDS ----------------
__device__ inline void gload_lds16(const void* g, void* lds) {
  __builtin_amdgcn_global_load_lds(
      (const __attribute__((address_space(1))) unsigned int*)g,
      (__attribute__((address_space(3))) unsigned int*)lds, 16, 0, 0);
}

// Stage one half-tile (256 rows x 32 k, 16KB) into a contiguous LDS region.
// LINEAR LDS dest; XOR swizzle applied by permuting the GLOBAL source
// (involution, rule 21): physical chunk pc = kc ^ ((row>>1)&3).
// R4/R7-verified: 0 bank conflicts on the swizzled ds_read_b128 pattern.
__device__ __forceinline__ void stage_half(unsigned short* reg, const unsigned short* gsrc,
                                           int row0, int kcol0, int wid, int lane) {
  #pragma unroll
  for (int i = 0; i < 2; i++) {
    int c = (wid * 2 + i) * 64 + lane;        // chunk index 0..1023
    int row = c >> 2;                         // 4 chunks (64B) per row
    int kc = (c & 3) ^ ((row >> 1) & 3);      // logical k-chunk at this physical slot
    gload_lds16(gsrc + (size_t)(row0 + row) * ND + kcol0 + kc * 8,
                (char*)reg + (size_t)c * 16);
  }
}

// One phase (UNFENCED): ds-read frag subtile (plain C++ loads) | issue 1
// half-tile stage | barrier | setprio(1) | 16 MFMA | setprio(0) | [vmcnt] |
// barrier.  NO lgkmcnt(0), NO sched_barrier: the compiler emits per-use
// counted lgkmcnt (m97 evidence) so MFMA[0] starts after its own operands
// land while the remaining reads drain UNDER the MFMA cluster. The previous
// rounds' lgkmcnt(0)+sched_barrier(0) fence (rule-18, needed only for asm
// reads) serialized all 12 reads before every cluster -- m141's failure mode.
#define PHASE(BUF, S, NH, STAGE_STMT, VM_STMT)                                          \
  {                                                                                     \
    const char* Ar = (const char*)&lds[BUF][0][S][0];                                   \
    const char* Br = (const char*)&lds[BUF][1][S][0];                                   \
    if (NH == 0) {                                                                      \
      _Pragma("unroll") for (int m = 0; m < 8; m++)                                     \
          afr[m] = *(const bf16x8*)(Ar + (wr * 128 + m * 16 + llo) * 64 + sw);          \
    }                                                                                   \
    bf16x8 b0 = *(const bf16x8*)(Br + (wc * 64 + (NH * 2 + 0) * 16 + llo) * 64 + sw);   \
    bf16x8 b1 = *(const bf16x8*)(Br + (wc * 64 + (NH * 2 + 1) * 16 + llo) * 64 + sw);   \
    STAGE_STMT;                                                                         \
    __builtin_amdgcn_s_barrier();                                                       \
    __builtin_amdgcn_s_setprio(1);                                                      \
    _Pragma("unroll") for (int m = 0; m < 8; m++) {                                     \
      acc[m][NH * 2 + 0] = __builtin_amdgcn_mfma_f32_16x16x32_bf16(                     \
          afr[m], b0, acc[m][NH * 2 + 0], 0, 0, 0);                                     \
      acc[m][NH * 2 + 1] = __builtin_amdgcn_mfma_f32_16x16x32_bf16(                     \
          afr[m], b1, acc[m][NH * 2 + 1], 0, 0, 0);                                     \
    }                                                                                   \
    __builtin_amdgcn_s_setprio(0);                                                      \
    VM_STMT;                                                                            \
    __builtin_amdgcn_s_barrier();                                                       \
  }

// ---------------- 8-phase 256^2 fused GEMM + row-min + own-dist ----------------
__global__ __launch_bounds__(512, 2) void gemm8_kernel(
    const unsigned short* __restrict__ xb, const unsigned short* __restrict__ cb,
    const float* __restrict__ xnorm, const float* __restrict__ cnorm,
    const int* __restrict__ labels,
    float* __restrict__ own, float* __restrict__ pmin) {
  // [buf][mat A=0/B=1][khalf][256 rows x 32 k] -- each khalf region is the
  // contiguous 16KB staging unit. 128 KiB total.
  __shared__ unsigned short lds[2][2][2][256 * 32];

  const int tid = threadIdx.x;
  const int lane = tid & 63;
  const int wid = tid >> 6;
  const int llo = lane & 15;
  const int lkc = lane >> 4;
  // un-swizzle on read: physical chunk = lkc ^ ((row>>1)&3); frag rows are
  // llo + 16*m and (16m>>1)&3 == 0, so llo alone determines it.
  const int sw = ((lkc ^ ((llo >> 1) & 3)) << 4);

  int bid = blockIdx.x;
  int swz = (bid & 7) * (NWG / 8) + (bid >> 3);
  const int brow0 = (swz / NCB) * BM;
  const int bcol0 = (swz % NCB) * BN;
  const int wr = wid >> 2, wc = wid & 3;  // 2x4 wave grid: wave output 128x64

  f32x4 acc[8][4];
  #pragma unroll
  for (int m = 0; m < 8; m++)
    #pragma unroll
    for (int n = 0; n < 4; n++)
      acc[m][n] = (f32x4){0.f, 0.f, 0.f, 0.f};

  // prologue: t0 (h1..h4) -> buf0, t1 (h1..h3) -> buf1.  h1=A.kh0, h2=B.kh0,
  // h3=A.kh1, h4=B.kh1.  14 loads/wave issued; vmcnt(6) -> t0's 8 landed.
  stage_half(&lds[0][0][0][0], xb, brow0, 0, wid, lane);
  stage_half(&lds[0][1][0][0], cb, bcol0, 0, wid, lane);
  stage_half(&lds[0][0][1][0], xb, brow0, 32, wid, lane);
  stage_half(&lds[0][1][1][0], cb, bcol0, 32, wid, lane);
  stage_half(&lds[1][0][0][0], xb, brow0, 64, wid, lane);
  stage_half(&lds[1][1][0][0], cb, bcol0, 64, wid, lane);
  stage_half(&lds[1][0][1][0], xb, brow0, 96, wid, lane);
  asm volatile("s_waitcnt vmcnt(6)" ::: "memory");
  __builtin_amdgcn_s_barrier();

  bf16x8 afr[8];

  // steady-state iterations: phases 1-4 compute t (buf0), 5-8 compute t+1 (buf1).
  // Stage order per iter: t+1.h4 | t+2.h1 | t+2.h2 | t+2.h3+vmcnt(6) |
  //                       t+2.h4 | t+3.h1 | t+3.h2 | t+3.h3+vmcnt(6)
  // Each staged region's last LDS read is in the immediately preceding phase
  // (verified region-by-region in R2/R3), so DMA writes never race reads.
  for (int it = 0; it < NIT - 1; ++it) {
    const int t = 2 * it;
    const int k1 = (t + 1) * BK, k2 = (t + 2) * BK, k3 = (t + 3) * BK;
    PHASE(0, 0, 0, stage_half(&lds[1][1][1][0], cb, bcol0, k1 + 32, wid, lane), (void)0)
    PHASE(0, 0, 1, stage_half(&lds[0][0][0][0], xb, brow0, k2, wid, lane), (void)0)
    PHASE(0, 1, 0, stage_half(&lds[0][1][0][0], cb, bcol0, k2, wid, lane), (void)0)
    PHASE(0, 1, 1, stage_half(&lds[0][0][1][0], xb, brow0, k2 + 32, wid, lane),
          asm volatile("s_waitcnt vmcnt(6)" ::: "memory"))
    PHASE(1, 0, 0, stage_half(&lds[0][1][1][0], cb, bcol0, k2 + 32, wid, lane), (void)0)
    PHASE(1, 0, 1, stage_half(&lds[1][0][0][0], xb, brow0, k3, wid, lane), (void)0)
    PHASE(1, 1, 0, stage_half(&lds[1][1][0][0], cb, bcol0, k3, wid, lane), (void)0)
    PHASE(1, 1, 1, stage_half(&lds[1][0][1][0], xb, brow0, k3 + 32, wid, lane),
          asm volatile("s_waitcnt vmcnt(6)" ::: "memory"))
  }
  // peeled last iteration (t = NT-2): only t+1.h4 left to stage; drain at P4.
  {
    const int k1 = (NT - 1) * BK;
    PHASE(0, 0, 0, stage_half(&lds[1][1][1][0], cb, bcol0, k1 + 32, wid, lane), (void)0)
    PHASE(0, 0, 1, (void)0, (void)0)
    PHASE(0, 1, 0, (void)0, (void)0)
    PHASE(0, 1, 1, (void)0, asm volatile("s_waitcnt vmcnt(0)" ::: "memory"))
    PHASE(1, 0, 0, (void)0, (void)0)
    PHASE(1, 0, 1, (void)0, (void)0)
    PHASE(1, 1, 0, (void)0, (void)0)
    PHASE(1, 1, 1, (void)0, (void)0)
  }

  // ---- epilogue: dist = xn + cn - 2*dot; own-col; per-row min ----
  // C/D layout: col = lane&15, row = (lane>>4)*4 + reg  (m89-verified)
  float cnr[4];
  int coln[4];
  #pragma unroll
  for (int n = 0; n < 4; n++) {
    coln[n] = bcol0 + wc * 64 + n * 16 + llo;
    cnr[n] = cnorm[coln[n]];
  }
  const int cslot = bcol0 / 64 + wc;
  #pragma unroll
  for (int m = 0; m < 8; m++) {
    #pragma unroll
    for (int j = 0; j < 4; j++) {
      int row = brow0 + wr * 128 + m * 16 + lkc * 4 + j;
      float xn = xnorm[row];
      int lbl = labels[row];
      float rmin = 1e38f;
      #pragma unroll
      for (int n = 0; n < 4; n++) {
        float d = xn + cnr[n] - 2.0f * acc[m][n][j];
        if (coln[n] == lbl) own[row] = d;  // exactly one writer per row
        else rmin = fminf(rmin, d);
      }
      rmin = fminf(rmin, __shfl_xor(rmin, 1));
      rmin = fminf(rmin, __shfl_xor(rmin, 2));
      rmin = fminf(rmin, __shfl_xor(rmin, 4));
      rmin = fminf(rmin, __shfl_xor(rmin, 8));
      if (llo == 0) pmin[(size_t)row * NSLOT + cslot] = rmin;
    }
  }
}

// ---------------- fallback: reg-staged 128^2 fused GEMM (small ws) ----------------
constexpr int FBM = 128, FBK = 32;
constexpr int FNWG = (NB / FBM) * (NC / FBM);
__global__ __launch_bounds__(256) void gemm_fb_kernel(
    const float* __restrict__ xf, const float* __restrict__ cf,
    const float* __restrict__ xnorm, const float* __restrict__ cnorm,
    const int* __restrict__ labels,
    float* __restrict__ own, float* __restrict__ pmin) {
  __shared__ alignas(16) unsigned short lA[FBM * FBK];
  __shared__ alignas(16) unsigned short lB[FBM * FBK];
  const int tid = threadIdx.x, lane = tid & 63, wid = tid >> 6;
  int bid = blockIdx.x;
  int swz = (bid & 7) * (FNWG >> 3) + (bid >> 3);
  const int brow0 = (swz / (NC / FBM)) * FBM;
  const int bcol0 = (swz % (NC / FBM)) * FBM;
  const int wr = wid >> 1, wc = wid & 1;
  f32x4 acc[4][4];
  #pragma unroll
  for (int m = 0; m < 4; m++)
    #pragma unroll
    for (int n = 0; n < 4; n++) acc[m][n] = (f32x4){0.f, 0.f, 0.f, 0.f};
  for (int k0 = 0; k0 < ND; k0 += FBK) {
    __syncthreads();
    int ar = tid >> 1, ac = (tid & 1) << 4;
    const float* ga = xf + (size_t)(brow0 + ar) * ND + k0 + ac;
    const float* gb = cf + (size_t)(bcol0 + ar) * ND + k0 + ac;
    usvec8 ua[2], ub[2];
    #pragma unroll
    for (int h = 0; h < 2; h++) {
      float4 p = *(const float4*)(ga + h * 8), q = *(const float4*)(ga + h * 8 + 4);
      ua[h][0] = f2bf(p.x); ua[h][1] = f2bf(p.y); ua[h][2] = f2bf(p.z); ua[h][3] = f2bf(p.w);
      ua[h][4] = f2bf(q.x); ua[h][5] = f2bf(q.y); ua[h][6] = f2bf(q.z); ua[h][7] = f2bf(q.w);
      float4 r = *(const float4*)(gb + h * 8), s = *(const float4*)(gb + h * 8 + 4);
      ub[h][0] = f2bf(r.x); ub[h][1] = f2bf(r.y); ub[h][2] = f2bf(r.z); ub[h][3] = f2bf(r.w);
      ub[h][4] = f2bf(s.x); ub[h][5] = f2bf(s.y); ub[h][6] = f2bf(s.z); ub[h][7] = f2bf(s.w);
    }
    *(usvec8*)&lA[ar * FBK + ac] = ua[0];
    *(usvec8*)&lA[ar * FBK + ac + 8] = ua[1];
    *(usvec8*)&lB[ar * FBK + ac] = ub[0];
    *(usvec8*)&lB[ar * FBK + ac + 8] = ub[1];
    __syncthreads();
    bf16x8 af[4], bf[4];
    #pragma unroll
    for (int m = 0; m < 4; m++)
      af[m] = *(const bf16x8*)&lA[(wr * 64 + m * 16 + (lane & 15)) * FBK + (lane >> 4) * 8];
    #pragma unroll
    for (int n = 0; n < 4; n++)
      bf[n] = *(const bf16x8*)&lB[(wc * 64 + n * 16 + (lane & 15)) * FBK + (lane >> 4) * 8];
    #pragma unroll
    for (int m = 0; m < 4; m++)
      #pragma unroll
      for (int n = 0; n < 4; n++)
        acc[m][n] = __builtin_amdgcn_mfma_f32_16x16x32_bf16(af[m], bf[n], acc[m][n], 0, 0, 0);
  }
  const int llo = lane & 15, lhi = lane >> 4;
  float cnr[4];
  int coln[4];
  #pragma unroll
  for (int n = 0; n < 4; n++) {
    coln[n] = bcol0 + wc * 64 + n * 16 + llo;
    cnr[n] = cnorm[coln[n]];
  }
  const int cslot = bcol0 / 64 + wc;
  #pragma unroll
  for (int m = 0; m < 4; m++)
    #pragma unroll
    for (int j = 0; j < 4; j++) {
      int row = brow0 + wr * 64 + m * 16 + lhi * 4 + j;
      float xn = xnorm[row];
      int lbl = labels[row];
      float rmin = 1e38f;
      #pragma unroll
      for (int n = 0; n < 4; n++) {
        float d = xn + cnr[n] - 2.0f * acc[m][n][j];
        if (coln[n] == lbl) own[row] = d;
        else rmin = fminf(rmin, d);
      }
      rmin = fminf(rmin, __shfl_xor(rmin, 1));
      rmin = fminf(rmin, __shfl_xor(rmin, 2));
      rmin = fminf(rmin, __shfl_xor(rmin, 4));
      rmin = fminf(rmin, __shfl_xor(rmin, 8));
      if (llo == 0) pmin[(size_t)row * NSLOT + cslot] = rmin;
    }
}

// ---------------- final: hinge + deterministic sum ----------------
__global__ __launch_bounds__(256) void finalize_kernel(const float* __restrict__ own,
                                                       const float* __restrict__ pmin,
                                                       const float* __restrict__ margin,
                                                       const float* __restrict__ wgt,
                                                       float* __restrict__ partial) {
  int r = blockIdx.x * 256 + threadIdx.x;
  const float4* p4 = (const float4*)(pmin + (size_t)r * NSLOT);
  float mn = 1e38f;
  #pragma unroll
  for (int i = 0; i < NSLOT / 4; i++) {
    float4 v = p4[i];
    mn = fminf(mn, fminf(fminf(v.x, v.y), fminf(v.z, v.w)));
  }
  float W = *wgt;
  float h = fmaxf(*margin + W * own[r] - (1.0f - W) * mn, 0.0f);
  #pragma unroll
  for (int m = 1; m < 64; m <<= 1) h += __shfl_xor(h, m);
  __shared__ float red[4];
  int lane = threadIdx.x & 63, wid = threadIdx.x >> 6;
  if (lane == 0) red[wid] = h;
  __syncthreads();
  if (threadIdx.x == 0) partial[blockIdx.x] = red[0] + red[1] + red[2] + red[3];
}

__global__ void final2_kernel(const float* __restrict__ partial, float* __restrict__ out) {
  float s = (threadIdx.x < NB / 256) ? partial[threadIdx.x] : 0.f;
  #pragma unroll
  for (int m = 1; m < 64; m <<= 1) s += __shfl_xor(s, m);
  if (threadIdx.x == 0) out[0] = s * (1.0f / NB);
}

extern "C" void kernel_launch(void* const* d_in, const int* in_sizes, int n_in,
                              void* d_out, int out_size, void* d_ws, size_t ws_size,
                              hipStream_t stream) {
  const float* x = (const float*)d_in[0];
  const float* cen = (const float*)d_in[1];
  const int* labels = (const int*)d_in[2];
  const float* margin = (const float*)d_in[3];
  const float* wgt = (const float*)d_in[4];
  float* out = (float*)d_out;

  char* base = (char*)d_ws;
  size_t off = 0;
  auto alloc = [&](size_t bytes) {
    void* q = base + off;
    off = (off + bytes + 255) & ~(size_t)255;
    return q;
  };
  float* xnorm = (float*)alloc((size_t)NB * 4);
  float* cnorm = (float*)alloc((size_t)NC * 4);
  float* own = (float*)alloc((size_t)NB * 4);
  float* pmin = (float*)alloc((size_t)NB * NSLOT * 4);
  float* partial = (float*)alloc(64 * 4);
  unsigned short* xb = (unsigned short*)alloc((size_t)NB * ND * 2);
  unsigned short* cb = (unsigned short*)alloc((size_t)NC * ND * 2);
  size_t need_big = off;  // ~52.9 MB

  if (ws_size >= need_big) {
    prep_kernel<<<NB + NC, 256, 0, stream>>>(x, cen, xnorm, cnorm, xb, cb);
    gemm8_kernel<<<NWG, 512, 0, stream>>>(xb, cb, xnorm, cnorm, labels, own, pmin);
  } else {
    norms_kernel<<<NB + NC, 256, 0, stream>>>(x, cen, xnorm, cnorm);
    gemm_fb_kernel<<<FNWG, 256, 0, stream>>>(x, cen, xnorm, cnorm, labels, own, pmin);
  }
  finalize_kernel<<<NB / 256, 256, 0, stream>>>(own, pmin, margin, wgt, partial);
  final2_kernel<<<1, 64, 0, stream>>>(partial, out);
}